// Round 7
// baseline (1146.109 us; speedup 1.0000x reference)
//
#include <hip/hip_runtime.h>
#include <hip/hip_bf16.h>

// ---------------------------------------------------------------------------
// WeightOnlyLinear: y = x @ dequant4(qweight, scales, qzeros) + bias
//   x (8192,4096) fp32 | scales (32,12288) | bias (12288) | qweight (512,12288)
//   qzeros (32,1536) | out (8192,12288) fp32
// R7: prepass dequant (R4-style) + 128x256 GEMM, 256 thr (4 waves 1Mx4N),
//     ring-3 x 24KB LDS (72KB/block) -> TWO co-resident blocks per CU so one
//     block's MFMA fills the other's barrier/vmcnt gaps. Same XOR swizzle,
//     counted vmcnt(6) per body, T1 + T5.
// ---------------------------------------------------------------------------

typedef __attribute__((ext_vector_type(8))) short short8;
typedef __attribute__((ext_vector_type(4))) float f32x4;

__device__ __forceinline__ short f2bf(float f) {
  unsigned u = __float_as_uint(f);
  u += 0x7fffu + ((u >> 16) & 1u);
  return (short)(u >> 16);
}

__device__ __forceinline__ void gload_lds16(const void* g, void* l) {
  __builtin_amdgcn_global_load_lds(
      (const __attribute__((address_space(1))) void*)g,
      (__attribute__((address_space(3))) void*)l,
      16, 0, 0);
}

__device__ __forceinline__ void bar() {
  asm volatile("" ::: "memory");
  __builtin_amdgcn_s_barrier();
  asm volatile("" ::: "memory");
}
__device__ __forceinline__ void wait_vm6() {
  asm volatile("s_waitcnt vmcnt(6)" ::: "memory");
}
__device__ __forceinline__ void wait_vm0() {
  asm volatile("s_waitcnt vmcnt(0)" ::: "memory");
}

// ---------------------------------------------------------------------------
// Pass 1: dequant + transpose. qweight (K/8, N) int32 -> Wt (N, K) bf16.
// ---------------------------------------------------------------------------
__global__ __launch_bounds__(256) void dequant_kernel(
    const int* __restrict__ qweight, const int* __restrict__ qzeros,
    const float* __restrict__ scales, short* __restrict__ Wt,
    int in_f, int out_f) {
  __shared__ __align__(16) short T[64][72];
  const int n0 = blockIdx.x * 64;
  const int k0 = blockIdx.y * 64;
  const int t = threadIdx.x;
  const int nl = t & 63;
  const int kw = t >> 6;
  const int n = n0 + nl;
  const int g = k0 >> 7;
  const float sc = scales[(size_t)g * out_f + n];
  const int zpw = qzeros[(size_t)g * (out_f >> 3) + (n >> 3)];
  const float zp = (float)(((zpw >> ((n & 7) * 4)) & 15) + 1);
  const float zs = zp * sc;
#pragma unroll
  for (int rr = 0; rr < 2; ++rr) {
    const int kwi = kw + rr * 4;
    const int w = qweight[(size_t)((k0 >> 3) + kwi) * out_f + n];
    short8 v;
#pragma unroll
    for (int e = 0; e < 8; ++e) {
      float f = (float)((w >> (4 * e)) & 15) * sc - zs;
      v[e] = f2bf(f);
    }
    *(short8*)&T[nl][kwi * 8] = v;
  }
  __syncthreads();
#pragma unroll
  for (int rr = 0; rr < 2; ++rr) {
    const int c = rr * 256 + t;
    const int row = c >> 3, ch = c & 7;
    *(short8*)&Wt[(size_t)(n0 + row) * in_f + k0 + ch * 8] =
        *(const short8*)&T[row][ch * 8];
  }
}

// ---------------------------------------------------------------------------
// Pass 2: x fp32 -> bf16.
// ---------------------------------------------------------------------------
__global__ __launch_bounds__(256) void cvt_kernel(
    const float* __restrict__ x, short* __restrict__ xb, long n8) {
  long i = (long)blockIdx.x * blockDim.x + threadIdx.x;
  if (i >= n8) return;
  const float* src = x + i * 8;
  float4 a = *(const float4*)src;
  float4 b = *(const float4*)(src + 4);
  short8 v;
  v[0] = f2bf(a.x); v[1] = f2bf(a.y); v[2] = f2bf(a.z); v[3] = f2bf(a.w);
  v[4] = f2bf(b.x); v[5] = f2bf(b.y); v[6] = f2bf(b.z); v[7] = f2bf(b.w);
  *(short8*)(xb + i * 8) = v;
}

// ---------------------------------------------------------------------------
// Pass 3 (R7): 128x256 GEMM, 256 threads = 4 waves (1M x 4N), wave 128x64.
// LDS: ring 3 x 24576 B. Slot: A[128 rows][32 k] bf16 @0 (8KB),
//      B[256 rows][32 k] bf16 @8192 (16KB). Chunk (row,q) at byte
//      region + row*64 + (q ^ ((row>>1)&3))*16 (R4-verified conflict-free).
// Body q (slot sl = q%3):
//   read bf[4] + af[0..3] (8x b128); stage phase q+2 -> slot (sl+2)%3
//   [6x gload: 2 A + 4 B]; 16 MFMA mh0; read af2[4]; 16 MFMA mh1.
// Ledger: entry outstanding 6 (phase q+1); +6 staged; exit vmcnt(6) -> phase
//   q+1 landed; bar. Tail: body P-2 exits vmcnt(0); body P-1 no sync.
// Two blocks/CU (72KB LDS, launch_bounds(256,2)) fill each other's gaps.
// ---------------------------------------------------------------------------
#define GBM 128
#define GBN 256

__global__ __launch_bounds__(256, 2) void gemm128x256_kernel(
    const short* __restrict__ A, const short* __restrict__ Bt,
    const float* __restrict__ bias, float* __restrict__ C,
    int M, int N, int K) {
  __shared__ __align__(16) char lds[3 * 24576];
  const int tid = threadIdx.x;
  const int nbx = N / GBN;
  const int nwg = gridDim.x;
  int bid = blockIdx.x;
  if ((nwg & 7) == 0) bid = (bid & 7) * (nwg >> 3) + (bid >> 3);  // T1
  const int bm = (bid / nbx) * GBM;
  const int bn = (bid % nbx) * GBN;

  const int wc = tid >> 6;  // wave = N-column group 0..3
  const int lane = tid & 63;
  const int lrow = lane & 15;
  const int lq = lane >> 4;

  const int P = K >> 5;  // phases (K-chunks of 32); P >= 4

  // ds_read bases (swizzle term invariant across frag index: +16 rows -> +8
  // in row>>1 -> 0 mod 4)
  const int swz = (lq ^ ((lrow >> 1) & 3)) * 16;
  const int baseA = lrow * 64 + swz;                    // + i*1024, i=0..7
  const int baseB = 8192 + (wc * 64 + lrow) * 64 + swz; // + j*1024, j=0..3

  // staging: A chunks c=tid, tid+256 (512 total); B chunks c=tid+256r (1024)
  // inverse-permuted global source (same involution as read side)
  const int cA0 = tid, cA1 = tid + 256;
  const int rA0 = cA0 >> 2, qA0 = (cA0 & 3) ^ ((rA0 >> 1) & 3);
  const int rA1 = cA1 >> 2, qA1 = (cA1 & 3) ^ ((rA1 >> 1) & 3);
  const short* srcA0 = A + (size_t)(bm + rA0) * K + qA0 * 8;
  const short* srcA1 = A + (size_t)(bm + rA1) * K + qA1 * 8;
  const int dA0 = cA0 * 16, dA1 = cA1 * 16;

  const short* srcB[4];
  int dB[4];
#pragma unroll
  for (int r = 0; r < 4; ++r) {
    const int c = tid + 256 * r;
    const int row = c >> 2, qq = (c & 3) ^ ((row >> 1) & 3);
    srcB[r] = Bt + (size_t)(bn + row) * K + qq * 8;
    dB[r] = 8192 + c * 16;
  }

  auto STAGE = [&](int slot, int q) {
    char* sb = &lds[slot * 24576];
    const int kof = q * 32;
    gload_lds16(srcA0 + kof, sb + dA0);
    gload_lds16(srcA1 + kof, sb + dA1);
#pragma unroll
    for (int r = 0; r < 4; ++r) gload_lds16(srcB[r] + kof, sb + dB[r]);
  };

  f32x4 acc[8][4] = {};

  auto BODY = [&](int sl, int qn, bool doStage) {
    const char* sb = &lds[sl * 24576];
    short8 bf[4], af[4];
#pragma unroll
    for (int j = 0; j < 4; ++j) bf[j] = *(const short8*)(sb + baseB + j * 1024);
#pragma unroll
    for (int i = 0; i < 4; ++i) af[i] = *(const short8*)(sb + baseA + i * 1024);
    if (doStage) STAGE(sl == 0 ? 2 : sl - 1, qn);  // (sl+2)%3
    __builtin_amdgcn_s_setprio(1);
#pragma unroll
    for (int i = 0; i < 4; ++i)
#pragma unroll
      for (int j = 0; j < 4; ++j)
        acc[i][j] = __builtin_amdgcn_mfma_f32_16x16x32_bf16(
            af[i], bf[j], acc[i][j], 0, 0, 0);
    __builtin_amdgcn_s_setprio(0);
    short8 af2[4];
#pragma unroll
    for (int i = 0; i < 4; ++i)
      af2[i] = *(const short8*)(sb + baseA + 4096 + i * 1024);
    __builtin_amdgcn_s_setprio(1);
#pragma unroll
    for (int i = 0; i < 4; ++i)
#pragma unroll
      for (int j = 0; j < 4; ++j)
        acc[4 + i][j] = __builtin_amdgcn_mfma_f32_16x16x32_bf16(
            af2[i], bf[j], acc[4 + i][j], 0, 0, 0);
    __builtin_amdgcn_s_setprio(0);
  };

  // prologue: stage phases 0,1 into slots 0,1 (12 loads); phase 0 landed at
  // vmcnt(6); bar
  STAGE(0, 0);
  STAGE(1, 1);
  wait_vm6();
  bar();

  int sl = 0;
  for (int q = 0; q < P; ++q) {
    BODY(sl, q + 2, q + 2 < P);
    if (q < P - 2) {
      wait_vm6();  // phase q+1 landed (its 6 loads oldest outstanding)
      bar();
    } else if (q == P - 2) {
      wait_vm0();  // phase P-1 landed
      bar();
    }
    sl = (sl == 2) ? 0 : sl + 1;
  }

  // epilogue: C = acc + bias. C/D map: col=lane&15, row=(lane>>4)*4+reg
  const int crow0 = bm + (lane >> 4) * 4;
  const int ccol0 = bn + wc * 64 + (lane & 15);
#pragma unroll
  for (int j = 0; j < 4; ++j) {
    const float bv = bias[ccol0 + j * 16];
#pragma unroll
    for (int i = 0; i < 8; ++i) {
#pragma unroll
      for (int r = 0; r < 4; ++r) {
        C[(size_t)(crow0 + i * 16 + r) * N + ccol0 + j * 16] =
            acc[i][j][r] + bv;
      }
    }
  }
}

// ---------------------------------------------------------------------------
// 128x128x64 GEMM (fallback for non-divisible shapes).
// ---------------------------------------------------------------------------
#define BM 128
#define BN 128
#define BK 64

template <bool A_BF16>
__global__ __launch_bounds__(256) void gemm_bias_kernel(
    const void* __restrict__ Av, const short* __restrict__ Bt,
    const float* __restrict__ bias, float* __restrict__ C,
    int M, int N, int K) {
  __shared__ __align__(16) short As[BM * BK];
  __shared__ __align__(16) short Bs[BN * BK];
  const int tid = threadIdx.x;
  const int bm = blockIdx.y * BM;
  const int bn = blockIdx.x * BN;
  const int wid = tid >> 6, lane = tid & 63;
  const int wr = wid >> 1, wc = wid & 1;
  const int lrow = lane & 15;
  const int lk = (lane >> 4) * 8;

  f32x4 acc[4][4] = {};

  for (int kt = 0; kt < K; kt += BK) {
    if constexpr (A_BF16) {
      const short* A = (const short*)Av;
#pragma unroll
      for (int r = 0; r < 4; ++r) {
        const int c = r * 256 + tid;
        const int row = c >> 3, ch = c & 7;
        gload_lds16(A + (size_t)(bm + row) * K + kt + ch * 8,
                    (char*)As + c * 16);
      }
    } else {
      const float* A = (const float*)Av;
#pragma unroll
      for (int r = 0; r < 4; ++r) {
        const int c = r * 256 + tid;
        const int row = c >> 3, ch = c & 7;
        const float* src = A + (size_t)(bm + row) * K + kt + ch * 8;
        float4 f0 = *(const float4*)src;
        float4 f1 = *(const float4*)(src + 4);
        short8 v;
        v[0] = f2bf(f0.x); v[1] = f2bf(f0.y); v[2] = f2bf(f0.z); v[3] = f2bf(f0.w);
        v[4] = f2bf(f1.x); v[5] = f2bf(f1.y); v[6] = f2bf(f1.z); v[7] = f2bf(f1.w);
        *(short8*)((char*)As + c * 16) = v;
      }
    }
#pragma unroll
    for (int r = 0; r < 4; ++r) {
      const int c = r * 256 + tid;
      const int row = c >> 3, ch = c & 7;
      gload_lds16(Bt + (size_t)(bn + row) * K + kt + ch * 8,
                  (char*)Bs + c * 16);
    }
    __syncthreads();
#pragma unroll
    for (int kk = 0; kk < 2; ++kk) {
      short8 af[4], bf[4];
#pragma unroll
      for (int i = 0; i < 4; ++i)
        af[i] = *(const short8*)&As[(wr * 64 + i * 16 + lrow) * BK + kk * 32 + lk];
#pragma unroll
      for (int j = 0; j < 4; ++j)
        bf[j] = *(const short8*)&Bs[(wc * 64 + j * 16 + lrow) * BK + kk * 32 + lk];
#pragma unroll
      for (int i = 0; i < 4; ++i)
#pragma unroll
        for (int j = 0; j < 4; ++j)
          acc[i][j] = __builtin_amdgcn_mfma_f32_16x16x32_bf16(
              af[i], bf[j], acc[i][j], 0, 0, 0);
    }
    __syncthreads();
  }

  const int crow0 = bm + wr * 64 + (lane >> 4) * 4;
  const int ccol0 = bn + wc * 64 + (lane & 15);
#pragma unroll
  for (int j = 0; j < 4; ++j) {
    const float bv = bias[ccol0 + j * 16];
#pragma unroll
    for (int i = 0; i < 4; ++i) {
#pragma unroll
      for (int r = 0; r < 4; ++r) {
        C[(size_t)(crow0 + i * 16 + r) * N + ccol0 + j * 16] = acc[i][j][r] + bv;
      }
    }
  }
}

// ---------------------------------------------------------------------------
// Last-resort fallback: naive fused dequant GEMM.
// ---------------------------------------------------------------------------
__global__ __launch_bounds__(256) void naive_kernel(
    const float* __restrict__ x, const float* __restrict__ scales,
    const float* __restrict__ bias, const int* __restrict__ qw,
    const int* __restrict__ qz, float* __restrict__ out,
    int M, int K, int N) {
  long idx = (long)blockIdx.x * blockDim.x + threadIdx.x;
  if (idx >= (long)M * N) return;
  const int n = (int)(idx % N);
  const int m = (int)(idx / N);
  float acc = 0.f;
  for (int g = 0; g < K / 128; ++g) {
    const float sc = scales[(size_t)g * N + n];
    const float zp =
        (float)(((qz[(size_t)g * (N >> 3) + (n >> 3)] >> ((n & 7) * 4)) & 15) + 1);
    const float zs = zp * sc;
    for (int kw = 0; kw < 16; ++kw) {
      const int w = qw[(size_t)(g * 16 + kw) * N + n];
      const float* xp = &x[(size_t)m * K + g * 128 + kw * 8];
#pragma unroll
      for (int e = 0; e < 8; ++e)
        acc += xp[e] * ((float)((w >> (4 * e)) & 15) * sc - zs);
    }
  }
  out[idx] = acc + bias[n];
}

// ---------------------------------------------------------------------------
extern "C" void kernel_launch(void* const* d_in, const int* in_sizes, int n_in,
                              void* d_out, int out_size, void* d_ws,
                              size_t ws_size, hipStream_t stream) {
  const float* x = (const float*)d_in[0];
  const float* scales = (const float*)d_in[1];
  const float* bias = (const float*)d_in[2];
  const int* qweight = (const int*)d_in[3];
  const int* qzeros = (const int*)d_in[4];
  float* out = (float*)d_out;

  const int out_f = in_sizes[2];            // 12288
  const int kwords = in_sizes[3] / out_f;   // 512
  const int in_f = kwords * 8;              // 4096
  const int tokens = in_sizes[0] / in_f;    // 8192
  const int M = tokens, K = in_f, N = out_f;

  const size_t wt_bytes = (size_t)K * N * sizeof(short);
  const size_t xb_bytes = (size_t)M * K * sizeof(short);

  const bool div128 = (M % BM == 0) && (N % BN == 0) && (K % BK == 0) &&
                      (K % 128 == 0) && (N % 64 == 0);
  const bool divR7 = (M % GBM == 0) && (N % GBN == 0) && (K % 128 == 0);

  if (div128 && ws_size >= wt_bytes + xb_bytes) {
    short* Wt = (short*)d_ws;
    short* xb = (short*)((char*)d_ws + wt_bytes);
    dequant_kernel<<<dim3(N / 64, K / 64), 256, 0, stream>>>(
        qweight, qzeros, scales, Wt, K, N);
    const long n8 = (long)M * K / 8;
    cvt_kernel<<<(int)((n8 + 255) / 256), 256, 0, stream>>>(x, xb, n8);
    if (divR7) {
      gemm128x256_kernel<<<(M / GBM) * (N / GBN), 256, 0, stream>>>(
          xb, Wt, bias, out, M, N, K);
    } else {
      gemm_bias_kernel<true><<<dim3(N / BN, M / BM), 256, 0, stream>>>(
          xb, Wt, bias, out, M, N, K);
    }
  } else if (div128 && ws_size >= wt_bytes) {
    short* Wt = (short*)d_ws;
    dequant_kernel<<<dim3(N / 64, K / 64), 256, 0, stream>>>(
        qweight, qzeros, scales, Wt, K, N);
    gemm_bias_kernel<false><<<dim3(N / BN, M / BM), 256, 0, stream>>>(
        x, Wt, bias, out, M, N, K);
  } else {
    const long total = (long)M * N;
    naive_kernel<<<(int)((total + 255) / 256), 256, 0, stream>>>(
        x, scales, bias, qweight, qzeros, out, M, K, N);
  }
}

// Round 8
// 908.902 us; speedup vs baseline: 1.2610x; 1.2610x over previous
//
#include <hip/hip_runtime.h>
#include <hip/hip_bf16.h>

// ---------------------------------------------------------------------------
// WeightOnlyLinear: y = x @ dequant4(qweight, scales, qzeros) + bias
//   x (8192,4096) fp32 | scales (32,12288) | bias (12288) | qweight (512,12288)
//   qzeros (32,1536) | out (8192,12288) fp32
// R8: R4 ring-of-4 skeleton (256x256, 8 waves, K-half slots, vmcnt(8)+1bar
//     per phase) with:
//     (a) mfma_f32_32x32x16_bf16 (faster pipe, half the MFMA instructions)
//     (b) x4-unrolled phases: ring slots compile-time, ds_reads = base VGPR +
//         immediate offset, stage pointers bumped once per iteration.
// ---------------------------------------------------------------------------

typedef __attribute__((ext_vector_type(8))) short short8;
typedef __attribute__((ext_vector_type(4))) float f32x4;
typedef __attribute__((ext_vector_type(16))) float f32x16;

__device__ __forceinline__ short f2bf(float f) {
  unsigned u = __float_as_uint(f);
  u += 0x7fffu + ((u >> 16) & 1u);
  return (short)(u >> 16);
}

__device__ __forceinline__ void gload_lds16(const void* g, void* l) {
  __builtin_amdgcn_global_load_lds(
      (const __attribute__((address_space(1))) void*)g,
      (__attribute__((address_space(3))) void*)l,
      16, 0, 0);
}

__device__ __forceinline__ void bar() {
  asm volatile("" ::: "memory");
  __builtin_amdgcn_s_barrier();
  asm volatile("" ::: "memory");
}
__device__ __forceinline__ void wait_vm8() {
  asm volatile("s_waitcnt vmcnt(8)" ::: "memory");
}
__device__ __forceinline__ void wait_vm4() {
  asm volatile("s_waitcnt vmcnt(4)" ::: "memory");
}
__device__ __forceinline__ void wait_vm0() {
  asm volatile("s_waitcnt vmcnt(0)" ::: "memory");
}

// ---------------------------------------------------------------------------
// Pass 1: dequant + transpose. qweight (K/8, N) int32 -> Wt (N, K) bf16.
// ---------------------------------------------------------------------------
__global__ __launch_bounds__(256) void dequant_kernel(
    const int* __restrict__ qweight, const int* __restrict__ qzeros,
    const float* __restrict__ scales, short* __restrict__ Wt,
    int in_f, int out_f) {
  __shared__ __align__(16) short T[64][72];
  const int n0 = blockIdx.x * 64;
  const int k0 = blockIdx.y * 64;
  const int t = threadIdx.x;
  const int nl = t & 63;
  const int kw = t >> 6;
  const int n = n0 + nl;
  const int g = k0 >> 7;
  const float sc = scales[(size_t)g * out_f + n];
  const int zpw = qzeros[(size_t)g * (out_f >> 3) + (n >> 3)];
  const float zp = (float)(((zpw >> ((n & 7) * 4)) & 15) + 1);
  const float zs = zp * sc;
#pragma unroll
  for (int rr = 0; rr < 2; ++rr) {
    const int kwi = kw + rr * 4;
    const int w = qweight[(size_t)((k0 >> 3) + kwi) * out_f + n];
    short8 v;
#pragma unroll
    for (int e = 0; e < 8; ++e) {
      float f = (float)((w >> (4 * e)) & 15) * sc - zs;
      v[e] = f2bf(f);
    }
    *(short8*)&T[nl][kwi * 8] = v;
  }
  __syncthreads();
#pragma unroll
  for (int rr = 0; rr < 2; ++rr) {
    const int c = rr * 256 + t;
    const int row = c >> 3, ch = c & 7;
    *(short8*)&Wt[(size_t)(n0 + row) * in_f + k0 + ch * 8] =
        *(const short8*)&T[row][ch * 8];
  }
}

// ---------------------------------------------------------------------------
// Pass 2: x fp32 -> bf16.
// ---------------------------------------------------------------------------
__global__ __launch_bounds__(256) void cvt_kernel(
    const float* __restrict__ x, short* __restrict__ xb, long n8) {
  long i = (long)blockIdx.x * blockDim.x + threadIdx.x;
  if (i >= n8) return;
  const float* src = x + i * 8;
  float4 a = *(const float4*)src;
  float4 b = *(const float4*)(src + 4);
  short8 v;
  v[0] = f2bf(a.x); v[1] = f2bf(a.y); v[2] = f2bf(a.z); v[3] = f2bf(a.w);
  v[4] = f2bf(b.x); v[5] = f2bf(b.y); v[6] = f2bf(b.z); v[7] = f2bf(b.w);
  *(short8*)(xb + i * 8) = v;
}

// ---------------------------------------------------------------------------
// Pass 3 (R8): 256x256 GEMM, 512 threads = 8 waves (2M x 4N), wave 128x64.
// LDS ring: 4 slots x 32KB (K-half h: A[256 rows][32 k] @0, B @16384).
// Chunk (row,q) at byte row*64 + (q ^ ((row>>1)&3))*16 (verified 0-conflict;
// 32x32 frag reads are 2-way per quarter-wave under the same swizzle).
// MFMA: 32x32x16 bf16. Wave tile = 4x2 frags of 32x32. Per K-32 phase:
//   12x ds_read_b128 (a0[4],b0[2],a1[4],b1[2]) + 4x global_load_lds (stage
//   K-half q+3) + 16 MFMA. vmcnt(8) + 1 barrier per phase (R4 ledger).
// Phases unrolled x4 -> slots compile-time, ds offsets immediate.
// ---------------------------------------------------------------------------
#define GBM 256
#define GBN 256

__global__ __launch_bounds__(512, 2) void gemm256_kernel(
    const short* __restrict__ A, const short* __restrict__ Bt,
    const float* __restrict__ bias, float* __restrict__ C,
    int M, int N, int K) {
  __shared__ __align__(16) char lds[4][32768];
  const int tid = threadIdx.x;
  const int nbx = N / GBN;
  const int nwg = gridDim.x;
  int bid = blockIdx.x;
  if ((nwg & 7) == 0) bid = (bid & 7) * (nwg >> 3) + (bid >> 3);  // T1
  const int bm = (bid / nbx) * GBM;
  const int bn = (bid % nbx) * GBN;

  const int wid = tid >> 6, lane = tid & 63;
  const int wr = wid >> 2, wc = wid & 3;  // 2x4 wave grid
  const int l31 = lane & 31;
  const int lq2 = lane >> 5;   // k-subchunk within K-16 (0/1)
  const int rs = (l31 >> 1) & 3;

  const int P = K >> 5;  // K-halves; P % 4 == 0, P >= 8

  char* lb = &lds[0][0];

  // --- ds_read base pointers: [hi(slot>=2)][kk]; slot bit0 + i*2048 are
  // immediate offsets. kk=1 flips chunk bit1 -> addr ^ 32.
  const int rowAl = wr * 128 + l31;                  // A region @0
  const int baseA0 = rowAl * 64 + ((0 * 2 + lq2) ^ rs) * 16;
  const int rowBl = wc * 64 + l31;                   // B region @16384
  const int baseB0 = 16384 + rowBl * 64 + ((0 * 2 + lq2) ^ rs) * 16;
  const char* aB[2][2];
  const char* bB[2][2];
  aB[0][0] = lb + baseA0;        aB[0][1] = lb + (baseA0 ^ 32);
  aB[1][0] = aB[0][0] + 65536;   aB[1][1] = aB[0][1] + 65536;
  bB[0][0] = lb + baseB0;        bB[0][1] = lb + (baseB0 ^ 32);
  bB[1][0] = bB[0][0] + 65536;   bB[1][1] = bB[0][1] + 65536;

  // --- stage addressing: A chunks c=tid,tid+512 in region @0; B same @16384.
  // Inverse-swizzled global source (same involution as read side).
  const int c0 = tid, c1 = tid + 512;
  const int rA0 = c0 >> 2, qA0 = (c0 & 3) ^ ((rA0 >> 1) & 3);
  const int rA1 = c1 >> 2, qA1 = (c1 & 3) ^ ((rA1 >> 1) & 3);
  const short* pA0 = A + (size_t)(bm + rA0) * K + qA0 * 8;
  const short* pA1 = A + (size_t)(bm + rA1) * K + qA1 * 8;
  const short* pB0 = Bt + (size_t)(bn + rA0) * K + qA0 * 8;
  const short* pB1 = Bt + (size_t)(bn + rA1) * K + qA1 * 8;
  char* dstA0 = lb + c0 * 16;
  char* dstA1 = lb + c1 * 16;
  char* dstB0 = lb + 16384 + c0 * 16;
  char* dstB1 = lb + 16384 + c1 * 16;

#define STAGE(NSL, KOF)                              \
  do {                                               \
    gload_lds16(pA0 + (KOF), dstA0 + (NSL) * 32768); \
    gload_lds16(pA1 + (KOF), dstA1 + (NSL) * 32768); \
    gload_lds16(pB0 + (KOF), dstB0 + (NSL) * 32768); \
    gload_lds16(pB1 + (KOF), dstB1 + (NSL) * 32768); \
  } while (0)

  f32x16 acc[4][2] = {};

  // one K-32 phase from slot SL (compile-time); stages K-half (SL+3) of the
  // current 4-phase window when ST.
#define PHASE(SL, ST)                                                         \
  do {                                                                        \
    short8 a0[4], a1[4], b0[2], b1[2];                                        \
    _Pragma("unroll") for (int i = 0; i < 4; ++i) a0[i] =                     \
        *(const short8*)(aB[(SL) >> 1][0] + ((SL)&1) * 32768 + i * 2048);     \
    _Pragma("unroll") for (int j = 0; j < 2; ++j) b0[j] =                     \
        *(const short8*)(bB[(SL) >> 1][0] + ((SL)&1) * 32768 + j * 2048);     \
    _Pragma("unroll") for (int i = 0; i < 4; ++i) a1[i] =                     \
        *(const short8*)(aB[(SL) >> 1][1] + ((SL)&1) * 32768 + i * 2048);     \
    _Pragma("unroll") for (int j = 0; j < 2; ++j) b1[j] =                     \
        *(const short8*)(bB[(SL) >> 1][1] + ((SL)&1) * 32768 + j * 2048);     \
    if (ST) STAGE(((SL) + 3) & 3, ((SL) + 3) * 32);                           \
    __builtin_amdgcn_s_setprio(1);                                            \
    _Pragma("unroll") for (int i = 0; i < 4; ++i)                             \
        _Pragma("unroll") for (int j = 0; j < 2; ++j) acc[i][j] =             \
            __builtin_amdgcn_mfma_f32_32x32x16_bf16(a0[i], b0[j], acc[i][j], \
                                                    0, 0, 0);                 \
    _Pragma("unroll") for (int i = 0; i < 4; ++i)                             \
        _Pragma("unroll") for (int j = 0; j < 2; ++j) acc[i][j] =             \
            __builtin_amdgcn_mfma_f32_32x32x16_bf16(a1[i], b1[j], acc[i][j], \
                                                    0, 0, 0);                 \
    __builtin_amdgcn_s_setprio(0);                                            \
  } while (0)

  // --- prologue: stage K-halves 0,1,2 into slots 0,1,2 (12 loads) ---
  STAGE(0, 0);
  STAGE(1, 32);
  STAGE(2, 64);

  // --- main loop: nIt iterations of 4 phases (q = 4it..4it+3, all stage) ---
  const int nIt = P / 4 - 1;
  for (int it = 0; it < nIt; ++it) {
    wait_vm8(); bar(); PHASE(0, true);
    wait_vm8(); bar(); PHASE(1, true);
    wait_vm8(); bar(); PHASE(2, true);
    wait_vm8(); bar(); PHASE(3, true);
    pA0 += 128; pA1 += 128; pB0 += 128; pB1 += 128;
  }
  // --- tail: q = P-4 (stages h P-1), then drain (ledger: 8/8/4/0) ---
  wait_vm8(); bar(); PHASE(0, true);
  wait_vm8(); bar(); PHASE(1, false);
  wait_vm4(); bar(); PHASE(2, false);
  wait_vm0(); bar(); PHASE(3, false);

#undef PHASE
#undef STAGE

  // --- epilogue: C = acc + bias.
  // 32x32 C/D map: col = lane&31, row = (reg&3) + 8*(reg>>2) + 4*(lane>>5)
  const int crow0 = bm + wr * 128 + 4 * lq2;
#pragma unroll
  for (int j = 0; j < 2; ++j) {
    const int ccol = bn + wc * 64 + j * 32 + l31;
    const float bv = bias[ccol];
#pragma unroll
    for (int i = 0; i < 4; ++i) {
#pragma unroll
      for (int reg = 0; reg < 16; ++reg) {
        const int row = crow0 + i * 32 + (reg & 3) + 8 * (reg >> 2);
        C[(size_t)row * N + ccol] = acc[i][j][reg] + bv;
      }
    }
  }
}

// ---------------------------------------------------------------------------
// 128x128x64 GEMM (fallback for non-256-divisible shapes).
// ---------------------------------------------------------------------------
#define BM 128
#define BN 128
#define BK 64

template <bool A_BF16>
__global__ __launch_bounds__(256) void gemm_bias_kernel(
    const void* __restrict__ Av, const short* __restrict__ Bt,
    const float* __restrict__ bias, float* __restrict__ C,
    int M, int N, int K) {
  __shared__ __align__(16) short As[BM * BK];
  __shared__ __align__(16) short Bs[BN * BK];
  const int tid = threadIdx.x;
  const int bm = blockIdx.y * BM;
  const int bn = blockIdx.x * BN;
  const int wid = tid >> 6, lane = tid & 63;
  const int wr = wid >> 1, wc = wid & 1;
  const int lrow = lane & 15;
  const int lk = (lane >> 4) * 8;

  f32x4 acc[4][4] = {};

  for (int kt = 0; kt < K; kt += BK) {
    if constexpr (A_BF16) {
      const short* A = (const short*)Av;
#pragma unroll
      for (int r = 0; r < 4; ++r) {
        const int c = r * 256 + tid;
        const int row = c >> 3, ch = c & 7;
        gload_lds16(A + (size_t)(bm + row) * K + kt + ch * 8,
                    (char*)As + c * 16);
      }
    } else {
      const float* A = (const float*)Av;
#pragma unroll
      for (int r = 0; r < 4; ++r) {
        const int c = r * 256 + tid;
        const int row = c >> 3, ch = c & 7;
        const float* src = A + (size_t)(bm + row) * K + kt + ch * 8;
        float4 f0 = *(const float4*)src;
        float4 f1 = *(const float4*)(src + 4);
        short8 v;
        v[0] = f2bf(f0.x); v[1] = f2bf(f0.y); v[2] = f2bf(f0.z); v[3] = f2bf(f0.w);
        v[4] = f2bf(f1.x); v[5] = f2bf(f1.y); v[6] = f2bf(f1.z); v[7] = f2bf(f1.w);
        *(short8*)((char*)As + c * 16) = v;
      }
    }
#pragma unroll
    for (int r = 0; r < 4; ++r) {
      const int c = r * 256 + tid;
      const int row = c >> 3, ch = c & 7;
      gload_lds16(Bt + (size_t)(bn + row) * K + kt + ch * 8,
                  (char*)Bs + c * 16);
    }
    __syncthreads();
#pragma unroll
    for (int kk = 0; kk < 2; ++kk) {
      short8 af[4], bf[4];
#pragma unroll
      for (int i = 0; i < 4; ++i)
        af[i] = *(const short8*)&As[(wr * 64 + i * 16 + lrow) * BK + kk * 32 + lk];
#pragma unroll
      for (int j = 0; j < 4; ++j)
        bf[j] = *(const short8*)&Bs[(wc * 64 + j * 16 + lrow) * BK + kk * 32 + lk];
#pragma unroll
      for (int i = 0; i < 4; ++i)
#pragma unroll
        for (int j = 0; j < 4; ++j)
          acc[i][j] = __builtin_amdgcn_mfma_f32_16x16x32_bf16(
              af[i], bf[j], acc[i][j], 0, 0, 0);
    }
    __syncthreads();
  }

  const int crow0 = bm + wr * 64 + (lane >> 4) * 4;
  const int ccol0 = bn + wc * 64 + (lane & 15);
#pragma unroll
  for (int j = 0; j < 4; ++j) {
    const float bv = bias[ccol0 + j * 16];
#pragma unroll
    for (int i = 0; i < 4; ++i) {
#pragma unroll
      for (int r = 0; r < 4; ++r) {
        C[(size_t)(crow0 + i * 16 + r) * N + ccol0 + j * 16] = acc[i][j][r] + bv;
      }
    }
  }
}

// ---------------------------------------------------------------------------
// Last-resort fallback: naive fused dequant GEMM.
// ---------------------------------------------------------------------------
__global__ __launch_bounds__(256) void naive_kernel(
    const float* __restrict__ x, const float* __restrict__ scales,
    const float* __restrict__ bias, const int* __restrict__ qw,
    const int* __restrict__ qz, float* __restrict__ out,
    int M, int K, int N) {
  long idx = (long)blockIdx.x * blockDim.x + threadIdx.x;
  if (idx >= (long)M * N) return;
  const int n = (int)(idx % N);
  const int m = (int)(idx / N);
  float acc = 0.f;
  for (int g = 0; g < K / 128; ++g) {
    const float sc = scales[(size_t)g * N + n];
    const float zp =
        (float)(((qz[(size_t)g * (N >> 3) + (n >> 3)] >> ((n & 7) * 4)) & 15) + 1);
    const float zs = zp * sc;
    for (int kw = 0; kw < 16; ++kw) {
      const int w = qw[(size_t)(g * 16 + kw) * N + n];
      const float* xp = &x[(size_t)m * K + g * 128 + kw * 8];
#pragma unroll
      for (int e = 0; e < 8; ++e)
        acc += xp[e] * ((float)((w >> (4 * e)) & 15) * sc - zs);
    }
  }
  out[idx] = acc + bias[n];
}

// ---------------------------------------------------------------------------
extern "C" void kernel_launch(void* const* d_in, const int* in_sizes, int n_in,
                              void* d_out, int out_size, void* d_ws,
                              size_t ws_size, hipStream_t stream) {
  const float* x = (const float*)d_in[0];
  const float* scales = (const float*)d_in[1];
  const float* bias = (const float*)d_in[2];
  const int* qweight = (const int*)d_in[3];
  const int* qzeros = (const int*)d_in[4];
  float* out = (float*)d_out;

  const int out_f = in_sizes[2];            // 12288
  const int kwords = in_sizes[3] / out_f;   // 512
  const int in_f = kwords * 8;              // 4096
  const int tokens = in_sizes[0] / in_f;    // 8192
  const int M = tokens, K = in_f, N = out_f;

  const size_t wt_bytes = (size_t)K * N * sizeof(short);
  const size_t xb_bytes = (size_t)M * K * sizeof(short);

  const bool div128 = (M % BM == 0) && (N % BN == 0) && (K % BK == 0) &&
                      (K % 128 == 0) && (N % 64 == 0);
  const bool div256 = (M % GBM == 0) && (N % GBN == 0) && (K % 256 == 0);

  if (div128 && ws_size >= wt_bytes + xb_bytes) {
    short* Wt = (short*)d_ws;
    short* xb = (short*)((char*)d_ws + wt_bytes);
    dequant_kernel<<<dim3(N / 64, K / 64), 256, 0, stream>>>(
        qweight, qzeros, scales, Wt, K, N);
    const long n8 = (long)M * K / 8;
    cvt_kernel<<<(int)((n8 + 255) / 256), 256, 0, stream>>>(x, xb, n8);
    if (div256) {
      gemm256_kernel<<<(M / GBM) * (N / GBN), 512, 0, stream>>>(
          xb, Wt, bias, out, M, N, K);
    } else {
      gemm_bias_kernel<true><<<dim3(N / BN, M / BM), 256, 0, stream>>>(
          xb, Wt, bias, out, M, N, K);
    }
  } else if (div128 && ws_size >= wt_bytes) {
    short* Wt = (short*)d_ws;
    dequant_kernel<<<dim3(N / 64, K / 64), 256, 0, stream>>>(
        qweight, qzeros, scales, Wt, K, N);
    gemm_bias_kernel<false><<<dim3(N / BN, M / BM), 256, 0, stream>>>(
        x, Wt, bias, out, M, N, K);
  } else {
    const long total = (long)M * N;
    naive_kernel<<<(int)((total + 255) / 256), 256, 0, stream>>>(
        x, scales, bias, qweight, qzeros, out, M, K, N);
  }
}